// Round 1
// baseline (619.562 us; speedup 1.0000x reference)
//
#include <hip/hip_runtime.h>
#include <math.h>

// Problem constants (from reference):
//   LAYER_SIZE=65536 (256x256 sheet), OUT_SIZE=2048 (first 8 rows), FILTER=5, INF_RATE=0.1
// Weights are masked by connectivity: dist((rm,cm),(rn,cn)) <= 5, rn in [0,8).
//   => rows rm>=13 are all-zero; rows rm<=12 have <=6 contiguous spans of <=11 floats.
// Exploiting the exact-zero structure is numerically exact (0*x adds 0.0f).

#define LAYER 65536
#define OUTN  2048

__global__ __launch_bounds__(256) void k_main(
    const float* __restrict__ bu, const float* __restrict__ r_act,
    const float* __restrict__ r_out, const float* __restrict__ x,
    const float* __restrict__ W, float* __restrict__ out,
    double* __restrict__ acc)
{
    const int m  = blockIdx.x * 256 + threadIdx.x;   // blockIdx.x == rm (256 thr/block)
    const int rm = m >> 8;
    const int cm = m & 255;

    float wx = 0.0f;
    if (rm <= 12) {  // block-uniform branch: only blocks 0..12 touch W
        // dcmax(|dr|) = floor(sqrt(25 - dr^2)) for dr = 0..5
        const int dctab[6] = {5, 4, 4, 4, 3, 0};
        int rn0 = rm - 5; if (rn0 < 0) rn0 = 0;
        int rn1 = rm + 5; if (rn1 > 7) rn1 = 7;
        const float* wbase = W + (size_t)m * OUTN;
        for (int rn = rn0; rn <= rn1; ++rn) {
            int dr = rm - rn; if (dr < 0) dr = -dr;
            const int dc = dctab[dr];
            int c0 = cm - dc; if (c0 < 0)   c0 = 0;
            int c1 = cm + dc; if (c1 > 255) c1 = 255;
            const float* wrow = wbase + (rn << 8);
            const float* xrow = x     + (rn << 8);
            for (int c = c0; c <= c1; ++c)
                wx = fmaf(wrow[c], xrow[c], wx);
        }
    }

    const float e  = r_out[m] - wx;                       // e_act
    const float ra = r_act[m] + 0.1f * (bu[m] - e);       // pre-threshold r_act
    out[m]         = e;
    out[LAYER + m] = ra;   // staged; finalize kernel overwrites with thresholded value

    // wave-64 shuffle reduction of sum / sumsq in double, then one atomic per wave
    double s  = (double)ra;
    double s2 = (double)ra * (double)ra;
    #pragma unroll
    for (int off = 32; off > 0; off >>= 1) {
        s  += __shfl_down(s,  off, 64);
        s2 += __shfl_down(s2, off, 64);
    }
    if ((threadIdx.x & 63) == 0) {
        atomicAdd(&acc[0], s);
        atomicAdd(&acc[1], s2);
    }
}

__global__ __launch_bounds__(256) void k_final(
    float* __restrict__ out, const double* __restrict__ acc)
{
    const int i = blockIdx.x * 256 + threadIdx.x;
    const double sum   = acc[0];
    const double sumsq = acc[1];
    const double mean  = sum * (1.0 / 65536.0);
    const double var   = (sumsq - sum * sum * (1.0 / 65536.0)) * (1.0 / 65535.0); // ddof=1
    const float cutoff = (float)(mean + 0.25 * sqrt(var));

    const float ra = out[LAYER + i];
    const float r2 = (ra < cutoff) ? -1.0f : ra;
    out[LAYER + i]     = r2;
    out[2 * LAYER + i] = tanhf(r2);
}

extern "C" void kernel_launch(void* const* d_in, const int* in_sizes, int n_in,
                              void* d_out, int out_size, void* d_ws, size_t ws_size,
                              hipStream_t stream)
{
    const float* bu    = (const float*)d_in[0];  // bu_errors      [65536]
    const float* r_act = (const float*)d_in[1];  // r_act          [65536]
    const float* r_out = (const float*)d_in[2];  // r_out          [65536]
    const float* x     = (const float*)d_in[3];  // nextlayer_r_out[2048]
    const float* W     = (const float*)d_in[4];  // weights        [65536,2048]
    float*  out = (float*)d_out;                 // [e_act | r_act | r_out_new], 3*65536
    double* acc = (double*)d_ws;                 // acc[0]=sum, acc[1]=sumsq

    // ws is re-poisoned to 0xAA before every timed launch — zero the accumulators.
    hipMemsetAsync(d_ws, 0, 2 * sizeof(double), stream);

    k_main <<<LAYER / 256, 256, 0, stream>>>(bu, r_act, r_out, x, W, out, acc);
    k_final<<<LAYER / 256, 256, 0, stream>>>(out, acc);
}

// Round 2
// 611.444 us; speedup vs baseline: 1.0133x; 1.0133x over previous
//
#include <hip/hip_runtime.h>
#include <math.h>

// Rf_PredLayer: e = r_out - W@x; ra = r_act + 0.1*(bu - e); threshold at mean+0.25*std(ddof=1); tanh.
// W (65536x2048 fp32, 512 MiB) is masked by connectivity dist<=5 on a 256-wide sheet with
// out rows rn in [0,8):
//   - rows rm>=13 of W are entirely zero  -> e[m] = r_out[m] exactly
//   - rows rm<=12: nonzeros live in rn in [rm-5, rm+5] ∩ [0,8), cols in [cm-5, cm+5] ∩ [0,256)
//     (outside-circle entries inside that window are STORED zeros -> multiplying them is exact)
// So the dense 512 MiB matvec reduces to ~3 MiB of touched data. Numerically exact (0*x adds 0.0f).
//
// Reduction: per-block (sum, sumsq) partials in double -> d_ws (fully overwritten, no memset
// dispatch, no same-address atomic serialization). k_final redundantly reduces the 256 partials
// per block (4 KiB, L2-hot) and applies threshold + tanh.

#define LAYER 65536

__global__ __launch_bounds__(256) void k_main(
    const float* __restrict__ bu, const float* __restrict__ r_act,
    const float* __restrict__ r_out, const float* __restrict__ x,
    const float* __restrict__ W, float* __restrict__ out,
    double* __restrict__ part)
{
    const int rm = blockIdx.x;            // 256 threads/block => blockIdx == sheet row of m
    const int cm = threadIdx.x;
    const int m  = (rm << 8) | cm;

    float wx = 0.0f;
    if (rm <= 12) {                        // block-uniform: only 13 of 256 blocks touch W
        int rn0 = rm - 5; if (rn0 < 0) rn0 = 0;
        int rn1 = rm + 5; if (rn1 > 7) rn1 = 7;
        int c0  = cm - 5; if (c0  < 0) c0  = 0;
        int c1  = cm + 5; if (c1 > 255) c1 = 255;
        const float* wbase = W + (size_t)m * 2048;
        for (int rn = rn0; rn <= rn1; ++rn) {
            const float* wrow = wbase + (rn << 8);
            const float* xrow = x     + (rn << 8);
            for (int c = c0; c <= c1; ++c)         // fixed 11-wide window; stored zeros outside circle
                wx = fmaf(wrow[c], xrow[c], wx);
        }
    }

    const float e  = r_out[m] - wx;
    const float ra = r_act[m] + 0.1f * (bu[m] - e);
    out[m]         = e;
    out[LAYER + m] = ra;                   // staged; k_final overwrites with thresholded value

    // block-level (sum, sumsq) in double: wave shuffle -> LDS -> one write per block
    double s  = (double)ra;
    double s2 = (double)ra * (double)ra;
    #pragma unroll
    for (int off = 32; off > 0; off >>= 1) {
        s  += __shfl_down(s,  off, 64);
        s2 += __shfl_down(s2, off, 64);
    }
    __shared__ double ls[4], ls2[4];
    const int w = threadIdx.x >> 6;
    if ((threadIdx.x & 63) == 0) { ls[w] = s; ls2[w] = s2; }
    __syncthreads();
    if (threadIdx.x == 0) {
        part[2 * blockIdx.x]     = ls[0] + ls[1] + ls[2] + ls[3];
        part[2 * blockIdx.x + 1] = ls2[0] + ls2[1] + ls2[2] + ls2[3];
    }
}

__global__ __launch_bounds__(256) void k_final(
    float* __restrict__ out, const double* __restrict__ part)
{
    __shared__ float s_cut;
    if (threadIdx.x < 64) {                // first wave: reduce 256 block-partials (L2-hot)
        double s = 0.0, s2 = 0.0;
        #pragma unroll
        for (int j = 0; j < 4; ++j) {
            const int k = threadIdx.x + 64 * j;
            s  += part[2 * k];
            s2 += part[2 * k + 1];
        }
        #pragma unroll
        for (int off = 32; off > 0; off >>= 1) {
            s  += __shfl_down(s,  off, 64);
            s2 += __shfl_down(s2, off, 64);
        }
        if (threadIdx.x == 0) {
            const double mean = s * (1.0 / 65536.0);
            const double var  = (s2 - s * s * (1.0 / 65536.0)) * (1.0 / 65535.0); // ddof=1
            s_cut = (float)(mean + 0.25 * sqrt(var));
        }
    }
    __syncthreads();

    const int i  = blockIdx.x * 256 + threadIdx.x;
    const float ra = out[LAYER + i];
    const float r2 = (ra < s_cut) ? -1.0f : ra;
    out[LAYER + i]     = r2;
    out[2 * LAYER + i] = tanhf(r2);
}

extern "C" void kernel_launch(void* const* d_in, const int* in_sizes, int n_in,
                              void* d_out, int out_size, void* d_ws, size_t ws_size,
                              hipStream_t stream)
{
    const float* bu    = (const float*)d_in[0];  // bu_errors       [65536]
    const float* r_act = (const float*)d_in[1];  // r_act           [65536]
    const float* r_out = (const float*)d_in[2];  // r_out           [65536]
    const float* x     = (const float*)d_in[3];  // nextlayer_r_out [2048]
    const float* W     = (const float*)d_in[4];  // weights         [65536,2048]
    float*  out  = (float*)d_out;                // [e_act | r_act | r_out_new]
    double* part = (double*)d_ws;                // 256 x {sum, sumsq} — fully overwritten each call

    k_main <<<256, 256, 0, stream>>>(bu, r_act, r_out, x, W, out, part);
    k_final<<<256, 256, 0, stream>>>(out, part);
}